// Round 2
// baseline (4312.962 us; speedup 1.0000x reference)
//
#include <hip/hip_runtime.h>
#include <math.h>

#define MR_C     256
#define MR_L     8192
#define MR_DEPTH 12
#define TPB      512
// each thread owns 4 float4 groups, strided TPB apart (coalesced)

__device__ __forceinline__ float4 f4z() { return make_float4(0.f, 0.f, 0.f, 0.f); }

// One level-step for one float4 group. LEV folds the dilation at compile time.
template<int LEV>
__device__ __forceinline__ void level_group(
    int g, float4& res, float4& acc,
    const float4* __restrict__ bc, float4* __restrict__ bn,
    const float4 F0, const float4 F1, const float wi)
{
    constexpr int d = 1 << LEV;
    const float4 rl = res;
    float4 t1, t2, t3;   // taps at t-d, t-2d, t-3d

    if constexpr (d == 1) {
        float4 p = (g >= 1) ? bc[g - 1] : f4z();
        t1 = make_float4(p.w, rl.x, rl.y, rl.z);
        t2 = make_float4(p.z, p.w, rl.x, rl.y);
        t3 = make_float4(p.y, p.z, p.w, rl.x);
    } else if constexpr (d == 2) {
        float4 p  = (g >= 1) ? bc[g - 1] : f4z();
        float4 p2 = (g >= 2) ? bc[g - 2] : f4z();
        t1 = make_float4(p.z, p.w, rl.x, rl.y);
        t2 = p;
        t3 = make_float4(p2.z, p2.w, p.x, p.y);
    } else {
        constexpr int d4 = d >> 2;   // d % 4 == 0: aligned float4 taps
        t1 = (g >= d4)     ? bc[g - d4]     : f4z();
        t2 = (g >= 2 * d4) ? bc[g - 2 * d4] : f4z();
        t3 = (g >= 3 * d4) ? bc[g - 3 * d4] : f4z();
    }

    // coefficient of x[t - d*j] is h[3-j]:  F.w*x[t] + F.z*x[t-d] + F.y*x[t-2d] + F.x*x[t-3d]
    float4 nl, hi;
    nl.x = F0.w * rl.x + F0.z * t1.x + F0.y * t2.x + F0.x * t3.x;
    nl.y = F0.w * rl.y + F0.z * t1.y + F0.y * t2.y + F0.x * t3.y;
    nl.z = F0.w * rl.z + F0.z * t1.z + F0.y * t2.z + F0.x * t3.z;
    nl.w = F0.w * rl.w + F0.z * t1.w + F0.y * t2.w + F0.x * t3.w;

    hi.x = F1.w * rl.x + F1.z * t1.x + F1.y * t2.x + F1.x * t3.x;
    hi.y = F1.w * rl.y + F1.z * t1.y + F1.y * t2.y + F1.x * t3.y;
    hi.z = F1.w * rl.z + F1.z * t1.z + F1.y * t2.z + F1.x * t3.z;
    hi.w = F1.w * rl.w + F1.z * t1.w + F1.y * t2.w + F1.x * t3.w;

    acc.x += wi * hi.x;
    acc.y += wi * hi.y;
    acc.z += wi * hi.z;
    acc.w += wi * hi.w;

    res = nl;
    if constexpr (LEV != MR_DEPTH - 1)   // last level's res_lo is consumed from registers only
        bn[g] = nl;
}

__global__ __launch_bounds__(TPB, 4) void multires_fused(
    const float* __restrict__ x,
    const float* __restrict__ h0,
    const float* __restrict__ h1,
    const float* __restrict__ w,
    float* __restrict__ out)
{
    __shared__ float4 buf0[MR_L / 4];
    __shared__ float4 buf1[MR_L / 4];

    const int row = blockIdx.x;            // b*C + c
    const int c   = row & (MR_C - 1);
    const int tid = threadIdx.x;

    // block-uniform filter/weight loads (scalar path, L2-cached)
    const float4 F0 = ((const float4*)h0)[c];
    const float4 F1 = ((const float4*)h1)[c];
    const float* __restrict__ wrow = w + c * (MR_DEPTH + 2);
    const float wlast = wrow[MR_DEPTH + 1];

    const float4* __restrict__ xrow = (const float4*)(x + (size_t)row * MR_L);
    const int g0 = tid, g1 = tid + TPB, g2 = tid + 2 * TPB, g3 = tid + 3 * TPB;

    float4 res0 = xrow[g0], res1 = xrow[g1], res2 = xrow[g2], res3 = xrow[g3];
    float4 acc0, acc1, acc2, acc3;
    acc0.x = res0.x * wlast; acc0.y = res0.y * wlast; acc0.z = res0.z * wlast; acc0.w = res0.w * wlast;
    acc1.x = res1.x * wlast; acc1.y = res1.y * wlast; acc1.z = res1.z * wlast; acc1.w = res1.w * wlast;
    acc2.x = res2.x * wlast; acc2.y = res2.y * wlast; acc2.z = res2.z * wlast; acc2.w = res2.w * wlast;
    acc3.x = res3.x * wlast; acc3.y = res3.y * wlast; acc3.z = res3.z * wlast; acc3.w = res3.w * wlast;
    buf0[g0] = res0; buf0[g1] = res1; buf0[g2] = res2; buf0[g3] = res3;
    __syncthreads();

    const float4* bc = buf0;
    float4*       bn = buf1;

#define DO_LEVEL(LEV)                                                          \
    {                                                                          \
        const float wi = wrow[MR_DEPTH - (LEV)];                               \
        level_group<LEV>(g0, res0, acc0, bc, bn, F0, F1, wi);                  \
        level_group<LEV>(g1, res1, acc1, bc, bn, F0, F1, wi);                  \
        level_group<LEV>(g2, res2, acc2, bc, bn, F0, F1, wi);                  \
        level_group<LEV>(g3, res3, acc3, bc, bn, F0, F1, wi);                  \
        __syncthreads();                                                       \
        const float4* tswap = bn; bn = (float4*)bc; bc = tswap;                \
    }

    DO_LEVEL(0)  DO_LEVEL(1)  DO_LEVEL(2)  DO_LEVEL(3)
    DO_LEVEL(4)  DO_LEVEL(5)  DO_LEVEL(6)  DO_LEVEL(7)
    DO_LEVEL(8)  DO_LEVEL(9)  DO_LEVEL(10) DO_LEVEL(11)
#undef DO_LEVEL

    // epilogue: y += w[:,0] * res_lo; exact-erf GELU; coalesced float4 store
    float4* __restrict__ orow = (float4*)(out + (size_t)row * MR_L);
    const float w0 = wrow[0];
    const float inv_sqrt2 = 0.70710678118654752f;

    float4 v; float u;
    u = acc0.x + w0 * res0.x; v.x = 0.5f * u * (1.0f + erff(u * inv_sqrt2));
    u = acc0.y + w0 * res0.y; v.y = 0.5f * u * (1.0f + erff(u * inv_sqrt2));
    u = acc0.z + w0 * res0.z; v.z = 0.5f * u * (1.0f + erff(u * inv_sqrt2));
    u = acc0.w + w0 * res0.w; v.w = 0.5f * u * (1.0f + erff(u * inv_sqrt2));
    orow[g0] = v;
    u = acc1.x + w0 * res1.x; v.x = 0.5f * u * (1.0f + erff(u * inv_sqrt2));
    u = acc1.y + w0 * res1.y; v.y = 0.5f * u * (1.0f + erff(u * inv_sqrt2));
    u = acc1.z + w0 * res1.z; v.z = 0.5f * u * (1.0f + erff(u * inv_sqrt2));
    u = acc1.w + w0 * res1.w; v.w = 0.5f * u * (1.0f + erff(u * inv_sqrt2));
    orow[g1] = v;
    u = acc2.x + w0 * res2.x; v.x = 0.5f * u * (1.0f + erff(u * inv_sqrt2));
    u = acc2.y + w0 * res2.y; v.y = 0.5f * u * (1.0f + erff(u * inv_sqrt2));
    u = acc2.z + w0 * res2.z; v.z = 0.5f * u * (1.0f + erff(u * inv_sqrt2));
    u = acc2.w + w0 * res2.w; v.w = 0.5f * u * (1.0f + erff(u * inv_sqrt2));
    orow[g2] = v;
    u = acc3.x + w0 * res3.x; v.x = 0.5f * u * (1.0f + erff(u * inv_sqrt2));
    u = acc3.y + w0 * res3.y; v.y = 0.5f * u * (1.0f + erff(u * inv_sqrt2));
    u = acc3.z + w0 * res3.z; v.z = 0.5f * u * (1.0f + erff(u * inv_sqrt2));
    u = acc3.w + w0 * res3.w; v.w = 0.5f * u * (1.0f + erff(u * inv_sqrt2));
    orow[g3] = v;
}

extern "C" void kernel_launch(void* const* d_in, const int* in_sizes, int n_in,
                              void* d_out, int out_size, void* d_ws, size_t ws_size,
                              hipStream_t stream) {
    const float* x  = (const float*)d_in[0];
    const float* h0 = (const float*)d_in[1];
    const float* h1 = (const float*)d_in[2];
    const float* w  = (const float*)d_in[3];
    float* o        = (float*)d_out;

    const int rows = in_sizes[0] / MR_L;   // B*C = 4096
    multires_fused<<<rows, TPB, 0, stream>>>(x, h0, h1, w, o);
}

// Round 3
// 3465.674 us; speedup vs baseline: 1.2445x; 1.2445x over previous
//
#include <hip/hip_runtime.h>
#include <math.h>

#define MR_C     256
#define MR_L     8192
#define MR_DEPTH 12
#define TPB      1024
// each thread owns 2 float4 groups, strided TPB apart (coalesced)

__device__ __forceinline__ float4 f4z() { return make_float4(0.f, 0.f, 0.f, 0.f); }

// One level-step for one float4 group. LEV folds the dilation at compile time.
template<int LEV>
__device__ __forceinline__ void level_group(
    int g, float4& res, float4& acc,
    const float4* __restrict__ bc, float4* __restrict__ bn,
    const float4 F0, const float4 F1, const float wi)
{
    constexpr int d = 1 << LEV;
    const float4 rl = res;
    float4 t1, t2, t3;   // taps at t-d, t-2d, t-3d

    if constexpr (d == 1) {
        float4 p = (g >= 1) ? bc[g - 1] : f4z();
        t1 = make_float4(p.w, rl.x, rl.y, rl.z);
        t2 = make_float4(p.z, p.w, rl.x, rl.y);
        t3 = make_float4(p.y, p.z, p.w, rl.x);
    } else if constexpr (d == 2) {
        float4 p  = (g >= 1) ? bc[g - 1] : f4z();
        float4 p2 = (g >= 2) ? bc[g - 2] : f4z();
        t1 = make_float4(p.z, p.w, rl.x, rl.y);
        t2 = p;
        t3 = make_float4(p2.z, p2.w, p.x, p.y);
    } else {
        constexpr int d4 = d >> 2;   // d % 4 == 0: aligned float4 taps
        t1 = (g >= d4)     ? bc[g - d4]     : f4z();
        t2 = (g >= 2 * d4) ? bc[g - 2 * d4] : f4z();
        t3 = (g >= 3 * d4) ? bc[g - 3 * d4] : f4z();
    }

    // coefficient of x[t - d*j] is h[3-j]:  F.w*x[t] + F.z*x[t-d] + F.y*x[t-2d] + F.x*x[t-3d]
    float4 nl, hi;
    nl.x = F0.w * rl.x + F0.z * t1.x + F0.y * t2.x + F0.x * t3.x;
    nl.y = F0.w * rl.y + F0.z * t1.y + F0.y * t2.y + F0.x * t3.y;
    nl.z = F0.w * rl.z + F0.z * t1.z + F0.y * t2.z + F0.x * t3.z;
    nl.w = F0.w * rl.w + F0.z * t1.w + F0.y * t2.w + F0.x * t3.w;

    hi.x = F1.w * rl.x + F1.z * t1.x + F1.y * t2.x + F1.x * t3.x;
    hi.y = F1.w * rl.y + F1.z * t1.y + F1.y * t2.y + F1.x * t3.y;
    hi.z = F1.w * rl.z + F1.z * t1.z + F1.y * t2.z + F1.x * t3.z;
    hi.w = F1.w * rl.w + F1.z * t1.w + F1.y * t2.w + F1.x * t3.w;

    acc.x += wi * hi.x;
    acc.y += wi * hi.y;
    acc.z += wi * hi.z;
    acc.w += wi * hi.w;

    res = nl;
    if constexpr (LEV != MR_DEPTH - 1)   // last level's res_lo is consumed from registers only
        bn[g] = nl;
}

// NOTE: no second __launch_bounds__ arg. Rounds 1-2 used (TPB,4), which forced a
// 64-VGPR cap -> ~40 regs spilled to scratch -> 14.5 GB HBM traffic -> 4.2 ms.
__global__ __launch_bounds__(TPB) void multires_fused(
    const float* __restrict__ x,
    const float* __restrict__ h0,
    const float* __restrict__ h1,
    const float* __restrict__ w,
    float* __restrict__ out)
{
    __shared__ float4 buf0[MR_L / 4];
    __shared__ float4 buf1[MR_L / 4];

    const int row = blockIdx.x;            // b*C + c
    const int c   = row & (MR_C - 1);
    const int tid = threadIdx.x;

    // block-uniform filter/weight loads (scalar path, L2-cached)
    const float4 F0 = ((const float4*)h0)[c];
    const float4 F1 = ((const float4*)h1)[c];
    const float* __restrict__ wrow = w + c * (MR_DEPTH + 2);
    const float wlast = wrow[MR_DEPTH + 1];

    const float4* __restrict__ xrow = (const float4*)(x + (size_t)row * MR_L);
    const int g0 = tid, g1 = tid + TPB;

    float4 res0 = xrow[g0], res1 = xrow[g1];
    float4 acc0, acc1;
    acc0.x = res0.x * wlast; acc0.y = res0.y * wlast; acc0.z = res0.z * wlast; acc0.w = res0.w * wlast;
    acc1.x = res1.x * wlast; acc1.y = res1.y * wlast; acc1.z = res1.z * wlast; acc1.w = res1.w * wlast;
    buf0[g0] = res0; buf0[g1] = res1;
    __syncthreads();

    const float4* bc = buf0;
    float4*       bn = buf1;

#define DO_LEVEL(LEV)                                                          \
    {                                                                          \
        const float wi = wrow[MR_DEPTH - (LEV)];                               \
        level_group<LEV>(g0, res0, acc0, bc, bn, F0, F1, wi);                  \
        level_group<LEV>(g1, res1, acc1, bc, bn, F0, F1, wi);                  \
        if ((LEV) != MR_DEPTH - 1) __syncthreads();                            \
        const float4* tswap = bn; bn = (float4*)bc; bc = tswap;                \
    }

    DO_LEVEL(0)  DO_LEVEL(1)  DO_LEVEL(2)  DO_LEVEL(3)
    DO_LEVEL(4)  DO_LEVEL(5)  DO_LEVEL(6)  DO_LEVEL(7)
    DO_LEVEL(8)  DO_LEVEL(9)  DO_LEVEL(10) DO_LEVEL(11)
#undef DO_LEVEL

    // epilogue: y += w[:,0] * res_lo; exact-erf GELU; coalesced float4 store
    float4* __restrict__ orow = (float4*)(out + (size_t)row * MR_L);
    const float w0 = wrow[0];
    const float inv_sqrt2 = 0.70710678118654752f;

    float4 v; float u;
    u = acc0.x + w0 * res0.x; v.x = 0.5f * u * (1.0f + erff(u * inv_sqrt2));
    u = acc0.y + w0 * res0.y; v.y = 0.5f * u * (1.0f + erff(u * inv_sqrt2));
    u = acc0.z + w0 * res0.z; v.z = 0.5f * u * (1.0f + erff(u * inv_sqrt2));
    u = acc0.w + w0 * res0.w; v.w = 0.5f * u * (1.0f + erff(u * inv_sqrt2));
    orow[g0] = v;
    u = acc1.x + w0 * res1.x; v.x = 0.5f * u * (1.0f + erff(u * inv_sqrt2));
    u = acc1.y + w0 * res1.y; v.y = 0.5f * u * (1.0f + erff(u * inv_sqrt2));
    u = acc1.z + w0 * res1.z; v.z = 0.5f * u * (1.0f + erff(u * inv_sqrt2));
    u = acc1.w + w0 * res1.w; v.w = 0.5f * u * (1.0f + erff(u * inv_sqrt2));
    orow[g1] = v;
}

extern "C" void kernel_launch(void* const* d_in, const int* in_sizes, int n_in,
                              void* d_out, int out_size, void* d_ws, size_t ws_size,
                              hipStream_t stream) {
    const float* x  = (const float*)d_in[0];
    const float* h0 = (const float*)d_in[1];
    const float* h1 = (const float*)d_in[2];
    const float* w  = (const float*)d_in[3];
    float* o        = (float*)d_out;

    const int rows = in_sizes[0] / MR_L;   // B*C = 4096
    multires_fused<<<rows, TPB, 0, stream>>>(x, h0, h1, w, o);
}